// Round 4
// baseline (316.797 us; speedup 1.0000x reference)
//
#include <hip/hip_runtime.h>
#include <math.h>

#define NN 10000
#define BB 4
#define EE 160000
#define CC 64
#define CE 16

// ---- workspace layout (bytes), total ~35.0 MB ----
static constexpr size_t OFF_XPA    = 0;           // float[NN*256]  xp transposed [n][c][b]
static constexpr size_t OFF_XPB    = 10240000;    // float[NN*256]  interlayer act (transposed)
static constexpr size_t OFF_AGG    = 20480000;    // float[NN*256]  aggr transposed [n][c][b]
static constexpr size_t OFF_SA     = 30720000;    // float[NN*BB]
static constexpr size_t OFF_SB     = 30880000;    // float[NN*BB]
static constexpr size_t OFF_VECS   = 31040000;    // float[288]
static constexpr size_t OFF_COUNTS = 31041280;    // int[NN]
static constexpr size_t OFF_CURSOR = 31081280;    // int[NN]
static constexpr size_t OFF_OFFS   = 31121280;    // int[NN+1] (+pad)
static constexpr size_t OFF_RECS   = 31161344;    // int2[EE]
static constexpr size_t OFF_ATT    = 32441344;    // float4[EE]

__device__ __forceinline__ float sigmoidf_(float x) {
    return 1.0f / (1.0f + __expf(-x));
}

// histogram of dst + (block 0) fold q@aw_q, k@aw_k, w_e@aw_e for both layers
__global__ void hist_vecs_kernel(const int* __restrict__ ei, int* __restrict__ counts,
                                 const float* __restrict__ q1, const float* __restrict__ k1,
                                 const float* __restrict__ aw1, const float* __restrict__ we1,
                                 const float* __restrict__ q2, const float* __restrict__ k2,
                                 const float* __restrict__ aw2, const float* __restrict__ we2,
                                 float* __restrict__ vecs) {
    int e = blockIdx.x * blockDim.x + threadIdx.x;
    if (e < EE) atomicAdd(&counts[ei[EE + e]], 1);
    if (blockIdx.x == 0) {
        int t = threadIdx.x;
        if (t < 64) {
            float a = 0.f, b = 0.f, c = 0.f, d = 0.f;
            for (int j = 0; j < 64; ++j) {
                a = fmaf(q1[t * 64 + j], aw1[j], a);
                b = fmaf(k1[t * 64 + j], aw1[64 + j], b);
                c = fmaf(q2[t * 64 + j], aw2[j], c);
                d = fmaf(k2[t * 64 + j], aw2[64 + j], d);
            }
            vecs[t] = a; vecs[64 + t] = b; vecs[144 + t] = c; vecs[208 + t] = d;
        }
        if (t < 16) {
            float a = 0.f, b = 0.f;
            for (int j = 0; j < 64; ++j) {
                a = fmaf(we1[t * 64 + j], aw1[128 + j], a);
                b = fmaf(we2[t * 64 + j], aw2[128 + j], b);
            }
            vecs[128 + t] = a; vecs[272 + t] = b;
        }
    }
}

// single-block exclusive scan via wave shuffles (3 syncs per 1024 chunk)
__global__ void scan_kernel(const int* __restrict__ counts, int* __restrict__ offs, int n) {
    __shared__ int wsum[16];
    __shared__ int carry_sh;
    int t = threadIdx.x;
    int lane = t & 63, wid = t >> 6;
    if (t == 0) carry_sh = 0;
    __syncthreads();
    for (int base = 0; base < n; base += 1024) {
        int i = base + t;
        int v = (i < n) ? counts[i] : 0;
        int x = v;
        #pragma unroll
        for (int d = 1; d < 64; d <<= 1) {
            int y = __shfl_up(x, d, 64);
            if (lane >= d) x += y;
        }
        if (lane == 63) wsum[wid] = x;
        __syncthreads();
        if (wid == 0 && lane < 16) {
            int s = wsum[lane];
            int y2 = s;
            #pragma unroll
            for (int d = 1; d < 16; d <<= 1) {
                int z = __shfl_up(y2, d, 16);
                if (lane >= d) y2 += z;
            }
            wsum[lane] = y2;  // inclusive
        }
        __syncthreads();
        int waveExcl = (wid == 0) ? 0 : wsum[wid - 1];
        int carry = carry_sh;
        if (i < n) offs[i] = carry + waveExcl + x - v;
        int total = wsum[15];
        __syncthreads();
        if (t == 0) carry_sh = carry + total;
        __syncthreads();
    }
    if (threadIdx.x == 0) offs[n] = carry_sh;
}

__global__ void scatter_kernel(const int* __restrict__ ei, const int* __restrict__ offs,
                               int* __restrict__ cursor, int2* __restrict__ recs) {
    int e = blockIdx.x * blockDim.x + threadIdx.x;
    if (e >= EE) return;
    int s = ei[e], d = ei[EE + e];
    int p = atomicAdd(&cursor[d], 1);
    recs[offs[d] + p] = make_int2(s, e);
}

// xp_t = transpose(x @ w_n) ; sa = xp@qa ; sb = xp@ka. One wave per node.
// IN_T: input laid out [n][c][b] (interlayer) vs [n][b][c] (original X).
template <bool IN_T>
__global__ __launch_bounds__(256) void node_prep_kernel(
    const float* __restrict__ x,
    const float* __restrict__ w_n, // [CC,CC]
    const float* __restrict__ qa,  // [64]
    const float* __restrict__ ka,  // [64]
    float* __restrict__ xp_t,      // [NN][CC][BB]
    float* __restrict__ sa,        // [NN,BB]
    float* __restrict__ sb) {
    __shared__ float w_sh[64 * 64];     // 16 KB
    __shared__ float x_sh[4 * BB * CC]; // 4 KB
    int t = threadIdx.x;
    for (int i = t; i < 64 * 64; i += 256) w_sh[i] = w_n[i];
    int node0 = blockIdx.x * 4;
    const float4* xg = (const float4*)(x + (size_t)node0 * BB * CC);
    ((float4*)x_sh)[t] = xg[t];
    __syncthreads();
    int wave = t >> 6, lane = t & 63;
    int node = node0 + wave;
    const float* xrow = x_sh + wave * BB * CC;
    float acc0 = 0.f, acc1 = 0.f, acc2 = 0.f, acc3 = 0.f;
    #pragma unroll 8
    for (int ci = 0; ci < 64; ++ci) {
        float w = w_sh[ci * 64 + lane];
        float x0 = IN_T ? xrow[ci * 4 + 0] : xrow[ci];
        float x1 = IN_T ? xrow[ci * 4 + 1] : xrow[64 + ci];
        float x2 = IN_T ? xrow[ci * 4 + 2] : xrow[128 + ci];
        float x3 = IN_T ? xrow[ci * 4 + 3] : xrow[192 + ci];
        acc0 = fmaf(x0, w, acc0);
        acc1 = fmaf(x1, w, acc1);
        acc2 = fmaf(x2, w, acc2);
        acc3 = fmaf(x3, w, acc3);
    }
    float4 st; st.x = acc0; st.y = acc1; st.z = acc2; st.w = acc3;
    *(float4*)(xp_t + (size_t)node * 256 + lane * 4) = st;
    float qv = qa[lane], kv = ka[lane];
    float ra0 = acc0 * qv, ra1 = acc1 * qv, ra2 = acc2 * qv, ra3 = acc3 * qv;
    float rb0 = acc0 * kv, rb1 = acc1 * kv, rb2 = acc2 * kv, rb3 = acc3 * kv;
    #pragma unroll
    for (int off = 32; off >= 1; off >>= 1) {
        ra0 += __shfl_xor(ra0, off, 64); ra1 += __shfl_xor(ra1, off, 64);
        ra2 += __shfl_xor(ra2, off, 64); ra3 += __shfl_xor(ra3, off, 64);
        rb0 += __shfl_xor(rb0, off, 64); rb1 += __shfl_xor(rb1, off, 64);
        rb2 += __shfl_xor(rb2, off, 64); rb3 += __shfl_xor(rb3, off, 64);
    }
    if (lane == 0) {
        sa[node * BB + 0] = ra0; sa[node * BB + 1] = ra1;
        sa[node * BB + 2] = ra2; sa[node * BB + 3] = ra3;
        sb[node * BB + 0] = rb0; sb[node * BB + 1] = rb1;
        sb[node * BB + 2] = rb2; sb[node * BB + 3] = rb3;
    }
}

// per-edge attention scalar: att4[e] = sigmoid(sa[src] + sb[dst] + attr[e]·weav + ab)
__global__ __launch_bounds__(256) void att_kernel(
    const int* __restrict__ ei, const float* __restrict__ attr,
    const float* __restrict__ sa, const float* __restrict__ sb,
    const float* __restrict__ weav,  // [16] (uniform)
    const float* __restrict__ ab,    // [1]
    float4* __restrict__ att) {
    int e = blockIdx.x * blockDim.x + threadIdx.x;
    if (e >= EE) return;
    int s = ei[e], d = ei[EE + e];
    const float4* ap = (const float4*)(attr + (size_t)e * CE);
    float4 a0 = ap[0], a1 = ap[1], a2 = ap[2], a3 = ap[3];
    float se = ab[0];
    se = fmaf(a0.x, weav[0], se);  se = fmaf(a0.y, weav[1], se);
    se = fmaf(a0.z, weav[2], se);  se = fmaf(a0.w, weav[3], se);
    se = fmaf(a1.x, weav[4], se);  se = fmaf(a1.y, weav[5], se);
    se = fmaf(a1.z, weav[6], se);  se = fmaf(a1.w, weav[7], se);
    se = fmaf(a2.x, weav[8], se);  se = fmaf(a2.y, weav[9], se);
    se = fmaf(a2.z, weav[10], se); se = fmaf(a2.w, weav[11], se);
    se = fmaf(a3.x, weav[12], se); se = fmaf(a3.y, weav[13], se);
    se = fmaf(a3.z, weav[14], se); se = fmaf(a3.w, weav[15], se);
    float4 sas = *(const float4*)(sa + (size_t)s * BB);
    float4 sbn = *(const float4*)(sb + (size_t)d * BB);
    float4 r;
    r.x = sigmoidf_(sas.x + sbn.x + se);
    r.y = sigmoidf_(sas.y + sbn.y + se);
    r.z = sigmoidf_(sas.z + sbn.z + se);
    r.w = sigmoidf_(sas.w + sbn.w + se);
    att[e] = r;
}

// Segment-max only. One wave per node, lane=channel, no LDS, no barrier.
__global__ __launch_bounds__(256) void aggr_kernel(
    const float* __restrict__ xp_t,    // [NN][CC][BB]
    const int2* __restrict__ recs,     // [EE] {src, e}
    const int* __restrict__ offs,      // [NN+1]
    const float* __restrict__ attr,    // [EE,CE]
    const float* __restrict__ w_e,     // [CE,CC]
    const float4* __restrict__ att,    // [EE]
    float* __restrict__ aggr_t) {      // [NN][CC][BB]
    int t = threadIdx.x;
    int wave = t >> 6, lane = t & 63;
    int node = blockIdx.x * 4 + wave;

    float wec[CE];
    #pragma unroll
    for (int j = 0; j < CE; ++j) wec[j] = w_e[j * CC + lane];

    int o0 = offs[node], o1 = offs[node + 1];
    float m0 = -INFINITY, m1 = -INFINITY, m2 = -INFINITY, m3 = -INFINITY;

    int i = o0;
    int2 rec = (i < o1) ? recs[i] : make_int2(0, 0);
    while (i < o1) {
        int2 cur = rec;
        ++i;
        if (i < o1) rec = recs[i];  // prefetch next
        int s = cur.x, e = cur.y;
        float4 at = att[e];
        float4 xv = *(const float4*)(xp_t + (size_t)s * 256 + lane * 4);
        const float4* ap = (const float4*)(attr + (size_t)e * CE);
        float4 a0 = ap[0], a1 = ap[1], a2 = ap[2], a3 = ap[3];
        float g = 0.f;
        g = fmaf(a0.x, wec[0], g);  g = fmaf(a0.y, wec[1], g);
        g = fmaf(a0.z, wec[2], g);  g = fmaf(a0.w, wec[3], g);
        g = fmaf(a1.x, wec[4], g);  g = fmaf(a1.y, wec[5], g);
        g = fmaf(a1.z, wec[6], g);  g = fmaf(a1.w, wec[7], g);
        g = fmaf(a2.x, wec[8], g);  g = fmaf(a2.y, wec[9], g);
        g = fmaf(a2.z, wec[10], g); g = fmaf(a2.w, wec[11], g);
        g = fmaf(a3.x, wec[12], g); g = fmaf(a3.y, wec[13], g);
        g = fmaf(a3.z, wec[14], g); g = fmaf(a3.w, wec[15], g);
        g = sigmoidf_(g);
        m0 = fmaxf(m0, at.x * xv.x * g);
        m1 = fmaxf(m1, at.y * xv.y * g);
        m2 = fmaxf(m2, at.z * xv.z * g);
        m3 = fmaxf(m3, at.w * xv.w * g);
    }
    m0 = (m0 == -INFINITY) ? 0.f : m0;
    m1 = (m1 == -INFINITY) ? 0.f : m1;
    m2 = (m2 == -INFINITY) ? 0.f : m2;
    m3 = (m3 == -INFINITY) ? 0.f : m3;
    float4 st; st.x = m0; st.y = m1; st.z = m2; st.w = m3;
    *(float4*)(aggr_t + (size_t)node * 256 + lane * 4) = st;
}

// Epilogue GEMM: out = leaky(xp + concat([xp,aggr])@ow + ob).
// WRITE_T: write transposed [n][c][b] (interlayer) vs [n][b][c] (final out).
template <bool WRITE_T>
__global__ __launch_bounds__(256) void out_kernel(
    const float* __restrict__ xp_t,    // [NN][CC][BB]
    const float* __restrict__ aggr_t,  // [NN][CC][BB]
    const float* __restrict__ ow,      // [2*CC,CC]
    const float* __restrict__ ob,      // [CC]
    float* __restrict__ out) {
    __shared__ float xs[4][BB * CC];   // [wave][b*64+c]
    __shared__ float as_[4][BB * CC];
    int t = threadIdx.x;
    int wave = t >> 6, lane = t & 63;
    int node = blockIdx.x * 4 + wave;

    float4 xv = *(const float4*)(xp_t + (size_t)node * 256 + lane * 4);
    float4 av = *(const float4*)(aggr_t + (size_t)node * 256 + lane * 4);
    xs[wave][0 * 64 + lane] = xv.x; xs[wave][1 * 64 + lane] = xv.y;
    xs[wave][2 * 64 + lane] = xv.z; xs[wave][3 * 64 + lane] = xv.w;
    as_[wave][0 * 64 + lane] = av.x; as_[wave][1 * 64 + lane] = av.y;
    as_[wave][2 * 64 + lane] = av.z; as_[wave][3 * 64 + lane] = av.w;
    __syncthreads();

    const float* xr = xs[wave];
    const float* ar = as_[wave];
    float o0f = 0.f, o1f = 0.f, o2f = 0.f, o3f = 0.f;
    #pragma unroll 4
    for (int ci = 0; ci < 64; ++ci) {
        float wa = ow[ci * 64 + lane];          // L1/L2-hot (32 KB total)
        float wb = ow[(64 + ci) * 64 + lane];
        o0f = fmaf(xr[ci], wa, o0f);
        o1f = fmaf(xr[64 + ci], wa, o1f);
        o2f = fmaf(xr[128 + ci], wa, o2f);
        o3f = fmaf(xr[192 + ci], wa, o3f);
        o0f = fmaf(ar[ci], wb, o0f);
        o1f = fmaf(ar[64 + ci], wb, o1f);
        o2f = fmaf(ar[128 + ci], wb, o2f);
        o3f = fmaf(ar[192 + ci], wb, o3f);
    }
    float obv = ob[lane];
    float r0 = xv.x + o0f + obv;
    float r1 = xv.y + o1f + obv;
    float r2 = xv.z + o2f + obv;
    float r3 = xv.w + o3f + obv;
    r0 = (r0 > 0.f) ? r0 : 0.01f * r0;
    r1 = (r1 > 0.f) ? r1 : 0.01f * r1;
    r2 = (r2 > 0.f) ? r2 : 0.01f * r2;
    r3 = (r3 > 0.f) ? r3 : 0.01f * r3;
    if (WRITE_T) {
        float4 st; st.x = r0; st.y = r1; st.z = r2; st.w = r3;
        *(float4*)(out + (size_t)node * 256 + lane * 4) = st;
    } else {
        float* op = out + (size_t)node * 256 + lane;
        op[0] = r0; op[64] = r1; op[128] = r2; op[192] = r3;
    }
}

extern "C" void kernel_launch(void* const* d_in, const int* in_sizes, int n_in,
                              void* d_out, int out_size, void* d_ws, size_t ws_size,
                              hipStream_t stream) {
    const float* X    = (const float*)d_in[0];
    const int*   ei   = (const int*)d_in[1];
    const float* attr = (const float*)d_in[2];
    const float* w_n1 = (const float*)d_in[3];
    const float* w_e1 = (const float*)d_in[4];
    const float* q1   = (const float*)d_in[5];
    const float* k1   = (const float*)d_in[6];
    const float* aw1  = (const float*)d_in[7];
    const float* ab1  = (const float*)d_in[8];
    const float* ow1  = (const float*)d_in[9];
    const float* ob1  = (const float*)d_in[10];
    const float* w_n2 = (const float*)d_in[11];
    const float* w_e2 = (const float*)d_in[12];
    const float* q2   = (const float*)d_in[13];
    const float* k2   = (const float*)d_in[14];
    const float* aw2  = (const float*)d_in[15];
    const float* ab2  = (const float*)d_in[16];
    const float* ow2  = (const float*)d_in[17];
    const float* ob2  = (const float*)d_in[18];
    float* out = (float*)d_out;

    char* ws = (char*)d_ws;
    float*  xpA    = (float*)(ws + OFF_XPA);
    float*  xpB    = (float*)(ws + OFF_XPB);
    float*  agg    = (float*)(ws + OFF_AGG);
    float*  sa     = (float*)(ws + OFF_SA);
    float*  sb     = (float*)(ws + OFF_SB);
    float*  vecs   = (float*)(ws + OFF_VECS);
    int*    counts = (int*)(ws + OFF_COUNTS);
    int*    cursor = (int*)(ws + OFF_CURSOR);
    int*    offs   = (int*)(ws + OFF_OFFS);
    int2*   recs   = (int2*)(ws + OFF_RECS);
    float4* att    = (float4*)(ws + OFF_ATT);

    // CSR build (edge_index is layer-invariant)
    hipMemsetAsync(counts, 0, 2 * NN * sizeof(int), stream);  // counts + cursor
    hist_vecs_kernel<<<EE / 256, 256, 0, stream>>>(ei, counts, q1, k1, aw1, w_e1,
                                                   q2, k2, aw2, w_e2, vecs);
    scan_kernel<<<1, 1024, 0, stream>>>(counts, offs, NN);
    scatter_kernel<<<EE / 256, 256, 0, stream>>>(ei, offs, cursor, recs);

    // layer 1
    node_prep_kernel<false><<<NN / 4, 256, 0, stream>>>(X, w_n1, vecs + 0, vecs + 64,
                                                        xpA, sa, sb);
    att_kernel<<<EE / 256, 256, 0, stream>>>(ei, attr, sa, sb, vecs + 128, ab1, att);
    aggr_kernel<<<NN / 4, 256, 0, stream>>>(xpA, recs, offs, attr, w_e1, att, agg);
    out_kernel<true><<<NN / 4, 256, 0, stream>>>(xpA, agg, ow1, ob1, xpB);

    // layer 2
    node_prep_kernel<true><<<NN / 4, 256, 0, stream>>>(xpB, w_n2, vecs + 144, vecs + 208,
                                                       xpA, sa, sb);
    att_kernel<<<EE / 256, 256, 0, stream>>>(ei, attr, sa, sb, vecs + 272, ab2, att);
    aggr_kernel<<<NN / 4, 256, 0, stream>>>(xpA, recs, offs, attr, w_e2, att, agg);
    out_kernel<false><<<NN / 4, 256, 0, stream>>>(xpA, agg, ow2, ob2, out);
}